// Round 10
// baseline (597.400 us; speedup 1.0000x reference)
//
#include <hip/hip_runtime.h>
#include <math.h>

// ============================================================================
// VisionAttention round 7 (3rd resubmit — three GPU-acquisition timeouts).
//   R6 post-mortem: attn pipeline worked (286->183us) but occupancy ~1 blk/CU
//   and zero cross-block TLP; proj GEMM's 2D XCD map regressed ~100us.
//   R7: attn -> 4-wave/64-row blocks, grid 1024, 3 blocks/CU (TLP); head-major
//   XCD map keeps one head's K+V L2-resident. proj GEMM reverted to R5 1D map.
//   Micro: exp2-domain softmax (log2e folded into K scale), cvt_pk P repack.
// ============================================================================

#define N_TOK 4096
#define DIMM  1280
#define NHEAD 16
#define HD    80
#define QKVN  3840
#define KP    3840   // packed K' = 3*DIMM for the hi/lo GEMM trick

typedef short bf16x8 __attribute__((ext_vector_type(8)));
typedef float f32x4  __attribute__((ext_vector_type(4)));

__device__ __forceinline__ unsigned short f2bf(float x) {
    unsigned int u = __float_as_uint(x);
    u += 0x7fff + ((u >> 16) & 1);           // RNE
    return (unsigned short)(u >> 16);
}
__device__ __forceinline__ float bf2f(unsigned short h) {
    return __uint_as_float(((unsigned int)h) << 16);
}
__device__ __forceinline__ void gload_lds16(const void* g, void* l) {
    __builtin_amdgcn_global_load_lds(
        (const __attribute__((address_space(1))) unsigned int*)g,
        (__attribute__((address_space(3))) unsigned int*)l, 16, 0, 0);
}
__device__ __forceinline__ unsigned int cvtpk_bf16(float a, float b) {
    unsigned int r;
    asm("v_cvt_pk_bf16_f32 %0, %1, %2" : "=v"(r) : "v"(a), "v"(b));
    return r;   // r[15:0]=bf16(a), r[31:16]=bf16(b)
}

#define MFMA16(a, b, c) __builtin_amdgcn_mfma_f32_16x16x32_bf16((a), (b), (c), 0, 0, 0)
#define EXP2(x) __builtin_amdgcn_exp2f(x)

// ---------------------------------------------------------------------------
// pack hidden: X[M][1280] fp32 -> Ap[M][3840] bf16 = [hi | lo | hi]
// ---------------------------------------------------------------------------
__global__ void pack_A_kernel(const float* __restrict__ X, unsigned short* __restrict__ Ap)
{
    const int idx = blockIdx.x * blockDim.x + threadIdx.x;
    if (idx >= N_TOK * DIMM / 4) return;
    const int e = idx * 4;
    const int m = e / DIMM, k = e - (e / DIMM) * DIMM;
    const float4 v = *reinterpret_cast<const float4*>(&X[(size_t)m * DIMM + k]);
    ushort4 hi, lo;
    hi.x = f2bf(v.x); lo.x = f2bf(v.x - bf2f(hi.x));
    hi.y = f2bf(v.y); lo.y = f2bf(v.y - bf2f(hi.y));
    hi.z = f2bf(v.z); lo.z = f2bf(v.z - bf2f(hi.z));
    hi.w = f2bf(v.w); lo.w = f2bf(v.w - bf2f(hi.w));
    const size_t base = (size_t)m * KP + k;
    *reinterpret_cast<ushort4*>(&Ap[base])            = hi;
    *reinterpret_cast<ushort4*>(&Ap[base + DIMM])     = lo;
    *reinterpret_cast<ushort4*>(&Ap[base + 2 * DIMM]) = hi;
}

// ---------------------------------------------------------------------------
// pack weight transposed: W[1280][Ncols] fp32 -> Bt[Ncols][3840] = [hi | hi | lo]
// ---------------------------------------------------------------------------
__global__ __launch_bounds__(256)
void pack_Bt_kernel(const float* __restrict__ W, unsigned short* __restrict__ Bt, int Ncols)
{
    __shared__ float Ts[32][33];
    const int k0 = blockIdx.x * 32, n0 = blockIdx.y * 32;
    const int t = threadIdx.x;
    const int r = t >> 3, c4 = (t & 7) * 4;
    const float4 v = *reinterpret_cast<const float4*>(&W[(size_t)(k0 + r) * Ncols + n0 + c4]);
    Ts[r][c4] = v.x; Ts[r][c4 + 1] = v.y; Ts[r][c4 + 2] = v.z; Ts[r][c4 + 3] = v.w;
    __syncthreads();
    float w0 = Ts[c4][r], w1 = Ts[c4 + 1][r], w2 = Ts[c4 + 2][r], w3 = Ts[c4 + 3][r];
    ushort4 hi, lo;
    hi.x = f2bf(w0); lo.x = f2bf(w0 - bf2f(hi.x));
    hi.y = f2bf(w1); lo.y = f2bf(w1 - bf2f(hi.y));
    hi.z = f2bf(w2); lo.z = f2bf(w2 - bf2f(hi.z));
    hi.w = f2bf(w3); lo.w = f2bf(w3 - bf2f(hi.w));
    const size_t base = (size_t)(n0 + r) * KP + k0 + c4;
    *reinterpret_cast<ushort4*>(&Bt[base])            = hi;
    *reinterpret_cast<ushort4*>(&Bt[base + DIMM])     = hi;
    *reinterpret_cast<ushort4*>(&Bt[base + 2 * DIMM]) = lo;
}

// ---------------------------------------------------------------------------
// bf16 MFMA GEMM (m97 structure).
// EPI==1 (qkv, 960 wg): 2D XCD tiling (kept — measured <= R5's 1D).
// EPI==0 (proj, 320 wg): R5 1D bijective swizzle (2D variant regressed).
// ---------------------------------------------------------------------------
template<int EPI>
__global__ __launch_bounds__(256)
void gemm_mfma(const unsigned short* __restrict__ A, const unsigned short* __restrict__ Bt,
               const float* __restrict__ bias, float* __restrict__ out, int Ncols)
{
    __shared__ unsigned short As[128 * 32];
    __shared__ unsigned short Bs[128 * 32];

    const int tid  = threadIdx.x;
    const int w    = tid >> 6, lane = tid & 63;

    const int lin = blockIdx.x;
    const int x   = lin & 7;
    const int l   = lin >> 3;
    int m0, n0;
    if (EPI == 1) {          // 960 wg = 32m x 30n; XCD x -> 8m x 15n block
        m0 = ((x >> 1) * 8 + (l & 7)) * 128;
        n0 = ((x & 1) * 15 + (l >> 3)) * 128;
    } else {                 // 320 wg: R5 1D bijective: wg = x*40 + l
        const int wg = x * 40 + l;
        m0 = (wg & 31) * 128;
        n0 = (wg >> 5) * 128;
    }

    const int wm   = w >> 1, wn = w & 1;
    const int lm   = lane & 15, kb = lane >> 4;

    const char* Ag = (const char*)(A  + (size_t)(m0 + w * 32 + (lane >> 2)) * KP) + (lane & 3) * 16;
    const char* Bg = (const char*)(Bt + (size_t)(n0 + w * 32 + (lane >> 2)) * KP) + (lane & 3) * 16;
    char* AsB = (char*)As + w * 2048;
    char* BsB = (char*)Bs + w * 2048;
    const size_t rowskip = (size_t)16 * KP * 2;

    f32x4 acc[4][4] = {};

    for (int k0 = 0; k0 < KP; k0 += 32) {
        const size_t kb2 = (size_t)k0 * 2;
        gload_lds16(Ag + kb2,           AsB);
        gload_lds16(Ag + kb2 + rowskip, AsB + 1024);
        gload_lds16(Bg + kb2,           BsB);
        gload_lds16(Bg + kb2 + rowskip, BsB + 1024);
        __syncthreads();

        bf16x8 a[4], b[4];
        #pragma unroll
        for (int mf = 0; mf < 4; ++mf)
            a[mf] = *reinterpret_cast<const bf16x8*>(&As[(wm * 64 + mf * 16 + lm) * 32 + kb * 8]);
        #pragma unroll
        for (int nf = 0; nf < 4; ++nf)
            b[nf] = *reinterpret_cast<const bf16x8*>(&Bs[(wn * 64 + nf * 16 + lm) * 32 + kb * 8]);
        #pragma unroll
        for (int mf = 0; mf < 4; ++mf)
            #pragma unroll
            for (int nf = 0; nf < 4; ++nf)
                acc[mf][nf] = MFMA16(a[mf], b[nf], acc[mf][nf]);
        __syncthreads();
    }

    #pragma unroll
    for (int nf = 0; nf < 4; ++nf) {
        const int col = n0 + wn * 64 + nf * 16 + lm;
        const float bb = bias[col];
        #pragma unroll
        for (int mf = 0; mf < 4; ++mf) {
            #pragma unroll
            for (int r = 0; r < 4; ++r) {
                const int row = m0 + wm * 64 + mf * 16 + kb * 4 + r;
                const float c = acc[mf][nf][r] + bb;
                if (EPI == 0) {
                    out[(size_t)row * Ncols + col] = c;
                } else {
                    const int part = col / DIMM;
                    const int rem  = col - part * DIMM;
                    const int hh   = rem / HD;
                    const int d    = rem - hh * HD;
                    out[(((size_t)(part * NHEAD + hh)) * N_TOK + row) * HD + d] = c;
                }
            }
        }
    }
}

// ---------------------------------------------------------------------------
// Rotary: q fp32 in place; K -> per-tile-contiguous bf16 hi/lo pack
// Kpk[h][tile128][plane2][32][104]; scale = log2(e)/sqrt(80) folded (exp2
// softmax domain); d-pad zeroed.
// ---------------------------------------------------------------------------
__global__ void rope_kernel(const float* __restrict__ freqs, float* __restrict__ q,
                            const float* __restrict__ k, unsigned short* __restrict__ Kpk)
{
    const int idx = blockIdx.x * blockDim.x + threadIdx.x;
    if (idx >= N_TOK * NHEAD * 40) return;
    const int dp = idx % 40;
    const int t  = idx / 40;
    const int h  = t & 15;
    const int n  = t >> 4;

    const float f = freqs[n * 40 + dp];
    const float c = cosf(f);
    const float s = sinf(f);

    const size_t base = ((size_t)h * N_TOK + n) * HD;
    const float q1 = q[base + dp], q2 = q[base + dp + 40];
    q[base + dp]      = q1 * c - q2 * s;
    q[base + dp + 40] = q2 * c + q1 * s;

    const float scale = 0.16129820579f;   // log2(e) / sqrt(80)
    const float k1 = k[base + dp], k2 = k[base + dp + 40];
    const float kr1 = (k1 * c - k2 * s) * scale;
    const float kr2 = (k2 * c + k1 * s) * scale;

    const int tile = n >> 5, r = n & 31;
    const size_t hi = ((size_t)(h * 128 + tile) * 2 + 0) * 3328 + r * 104;
    const size_t lo = ((size_t)(h * 128 + tile) * 2 + 1) * 3328 + r * 104;
    const unsigned short h1 = f2bf(kr1);
    Kpk[hi + dp]      = h1;
    Kpk[lo + dp]      = f2bf(kr1 - bf2f(h1));
    const unsigned short h2 = f2bf(kr2);
    Kpk[hi + dp + 40] = h2;
    Kpk[lo + dp + 40] = f2bf(kr2 - bf2f(h2));
    if (dp < 12) {
        Kpk[hi + 80 + dp] = 0; Kpk[hi + 92 + dp] = 0;
        Kpk[lo + 80 + dp] = 0; Kpk[lo + 92 + dp] = 0;
    }
}

// ---------------------------------------------------------------------------
// V^T pack with KEY-SLOT PERMUTATION: Vt[h][tile][2][80][40] bf16, where
// column slot s holds key kappa(s) = ((s&7)<4 ? 0:16) + 4*(s>>3) + (s&3).
// ---------------------------------------------------------------------------
__global__ __launch_bounds__(256)
void vpack_kernel(const float* __restrict__ v, unsigned short* __restrict__ Vt)
{
    __shared__ float T[32][81];
    const int t = blockIdx.x, h = blockIdx.y;
    const int kt = t * 32;
    for (int e = threadIdx.x; e < 32 * 80; e += 256) {
        const int key = e / 80, d = e - (e / 80) * 80;
        T[key][d] = v[((size_t)h * N_TOK + kt + key) * HD + d];
    }
    __syncthreads();
    unsigned short* base = Vt + ((size_t)h * 128 + t) * 6400;
    for (int e = threadIdx.x; e < 3200; e += 256) {
        const int d = e / 40, col = e - (e / 40) * 40;
        float x = 0.f;
        if (col < 32) {
            const int key = (((col & 7) < 4) ? 0 : 16) + 4 * (col >> 3) + (col & 3);
            x = T[key][d];
        }
        const unsigned short hi = f2bf(x);
        base[e]        = hi;
        base[3200 + e] = f2bf(x - bf2f(hi));
    }
}

// ---------------------------------------------------------------------------
// MFMA flash attention: swapped QK^T, in-register P, counted-vmcnt depth-1
// pipeline, 4 waves x 16 q-rows = 64 rows/block, grid 1024 -> 3 blocks/CU.
// Softmax in exp2 domain (log2e pre-folded into K). LDS 52224 B (2 bufs).
// ---------------------------------------------------------------------------
__global__ __launch_bounds__(256)
void attn_mfma(const float* __restrict__ qbuf, const unsigned short* __restrict__ Kpk,
               const unsigned short* __restrict__ Vt, const int* __restrict__ cu,
               unsigned short* __restrict__ Ap)
{
    __shared__ __align__(16) unsigned short KS[2][6656];   // [buf][plane2*32*104]
    __shared__ __align__(16) unsigned short VS[2][6400];   // [buf][plane2*80*40]

    const int tid  = threadIdx.x;
    const int w    = tid >> 6, lane = tid & 63;
    const int lm   = lane & 15, g = lane >> 4;

    // head-major XCD map: XCD x works head 2x for lin<512, then 2x+1
    // -> one head's K+V (3.35 MB) L2-resident per XCD at a time
    const int lin = blockIdx.x;
    const int h   = (lin & 7) * 2 + (lin >> 9);
    const int q0  = ((lin >> 3) & 63) * 64;

    const int c1 = cu[1], c2 = cu[2], c3 = cu[3];
    #define SEGOF(n) ((int)((n) >= c1) + (int)((n) >= c2) + (int)((n) >= c3))
    const int seg_first = SEGOF(q0);
    const int seg_last  = SEGOF(q0 + 63);
    const int cuv[5] = {0, c1, c2, c3, N_TOK};
    const int kmin = cuv[seg_first], kmax = cuv[seg_last + 1];
    const int kt0 = kmin & ~31;
    const int t0  = kt0 >> 5;
    const int ntiles = (kmax - kt0 + 31) >> 5;

    const size_t hb = (size_t)h * N_TOK;

    // --- Q fragments hi/lo (B-operand: lane&15 = q-col, g = k-chunk)
    bf16x8 qh[3], ql[3];
    const int qrow = q0 + w * 16 + lm;
    {
        const float* qp = qbuf + (hb + qrow) * HD;
        #pragma unroll
        for (int ks = 0; ks < 3; ++ks) {
            #pragma unroll
            for (int j = 0; j < 8; ++j) {
                const int d = ks * 32 + g * 8 + j;
                const float x = (d < HD) ? qp[d] : 0.f;
                const unsigned short hi = f2bf(x);
                qh[ks][j] = (short)hi;
                ql[ks][j] = (short)f2bf(x - bf2f(hi));
            }
        }
    }
    const int sq  = SEGOF(qrow);
    const int klo = cuv[sq], khi = cuv[sq + 1];

    float mrow = -1e30f, lrow = 0.f;
    f32x4 accO[5] = {};

    // --- async staging: 26 chunks (13 K + 12.5 V), 4 waves: w0,w1:7  w2,w3:6
    auto issue = [&](int buf, int tg) {
        const char* sK = (const char*)(Kpk + ((size_t)(h * 128 + tg) * 2) * 3328);
        const char* sV = (const char*)(Vt  +  (size_t)(h * 128 + tg) * 6400);
        char* dK = (char*)&KS[buf][0];
        char* dV = (char*)&VS[buf][0];
        for (int j = w; j < 26; j += 4) {
            if (j < 13) {
                gload_lds16(sK + j * 1024 + (size_t)lane * 16, dK + j * 1024);
            } else if (j < 25) {
                gload_lds16(sV + (j - 13) * 1024 + (size_t)lane * 16, dV + (j - 13) * 1024);
            } else if (lane < 32) {
                gload_lds16(sV + 12288 + (size_t)lane * 16, dV + 12288);
            }
        }
    };

    issue(0, t0);
    if (ntiles > 1) issue(1, t0 + 1);

    for (int ti = 0; ti < ntiles; ++ti) {
        const int buf = ti & 1;
        const int kt  = kt0 + ti * 32;

        // counted wait: tile-ti loads landed; tile-ti+1's stay in flight
        if (ti + 1 < ntiles) {
            if (w < 2) asm volatile("s_waitcnt vmcnt(7)" ::: "memory");
            else       asm volatile("s_waitcnt vmcnt(6)" ::: "memory");
        } else {
            asm volatile("s_waitcnt vmcnt(0)" ::: "memory");
        }
        __builtin_amdgcn_s_barrier();      // all waves' ti loads landed
        asm volatile("" ::: "memory");

        const unsigned short* Kb = &KS[buf][0];
        const unsigned short* Vb = &VS[buf][0];

        // ---- S^T = K @ Q^T : lane holds S[q=lm][keys 4g+r | 16+4g+r]
        f32x4 s0 = {0.f, 0.f, 0.f, 0.f}, s1 = {0.f, 0.f, 0.f, 0.f};
        #pragma unroll
        for (int ks = 0; ks < 3; ++ks) {
            const bf16x8 k0h = *reinterpret_cast<const bf16x8*>(&Kb[lm * 104 + ks * 32 + g * 8]);
            const bf16x8 k0l = *reinterpret_cast<const bf16x8*>(&Kb[3328 + lm * 104 + ks * 32 + g * 8]);
            const bf16x8 k1h = *reinterpret_cast<const bf16x8*>(&Kb[(16 + lm) * 104 + ks * 32 + g * 8]);
            const bf16x8 k1l = *reinterpret_cast<const bf16x8*>(&Kb[3328 + (16 + lm) * 104 + ks * 32 + g * 8]);
            s0 = MFMA16(k0h, qh[ks], s0);
            s0 = MFMA16(k0h, ql[ks], s0);
            s0 = MFMA16(k0l, qh[ks], s0);
            s1 = MFMA16(k1h, qh[ks], s1);
            s1 = MFMA16(k1h, ql[ks], s1);
            s1 = MFMA16(k1l, qh[ks], s1);
        }

        // ---- per-reg key validity (q-row segment bounds, hoisted)
        bool v0m[4], v1m[4];
        #pragma unroll
        for (int r = 0; r < 4; ++r) {
            const int j0 = kt + g * 4 + r;
            const int j1 = j0 + 16;
            v0m[r] = (j0 >= klo) && (j0 < khi);
            v1m[r] = (j1 >= klo) && (j1 < khi);
        }

        // ---- row max: in-reg + 2 shfls (S is in log2 units)
        float tm = -1e30f;
        #pragma unroll
        for (int r = 0; r < 4; ++r)
            tm = fmaxf(tm, fmaxf(v0m[r] ? s0[r] : -1e30f, v1m[r] ? s1[r] : -1e30f));
        tm = fmaxf(tm, __shfl_xor(tm, 16));
        tm = fmaxf(tm, __shfl_xor(tm, 32));

        // ---- defer-max: skip rescale when max growth <= 11.5 (= e^8 bound)
        const bool defer = __all(tm <= mrow + 11.5f);
        if (!defer) {
            const float mn = fmaxf(mrow, tm);
            const float sc = EXP2(mrow - mn);
            mrow = mn;
            lrow *= sc;
            float scq[4];
            #pragma unroll
            for (int r = 0; r < 4; ++r) scq[r] = __shfl(sc, ((lane >> 4) << 2) + r);
            #pragma unroll
            for (int f = 0; f < 5; ++f) {
                accO[f][0] *= scq[0]; accO[f][1] *= scq[1];
                accO[f][2] *= scq[2]; accO[f][3] *= scq[3];
            }
        }

        // ---- P = 2^(S - m), row sum
        float p0[4], p1[4], rs = 0.f;
        #pragma unroll
        for (int r = 0; r < 4; ++r) {
            p0[r] = v0m[r] ? EXP2(s0[r] - mrow) : 0.f;
            p1[r] = v1m[r] ? EXP2(s1[r] - mrow) : 0.f;
            rs += p0[r] + p1[r];
        }
        rs += __shfl_xor(rs, 16);
        rs += __shfl_xor(rs, 32);
        lrow += rs;

        // ---- A-fragment: pure local repack via v_cvt_pk_bf16_f32
        union { unsigned int u[4]; bf16x8 v; } pau;
        pau.u[0] = cvtpk_bf16(p0[0], p0[1]);
        pau.u[1] = cvtpk_bf16(p0[2], p0[3]);
        pau.u[2] = cvtpk_bf16(p1[0], p1[1]);
        pau.u[3] = cvtpk_bf16(p1[2], p1[3]);
        const bf16x8 pa = pau.v;

        // ---- O += P @ (Vh + Vl)
        #pragma unroll
        for (int f = 0; f < 5; ++f) {
            const bf16x8 vh = *reinterpret_cast<const bf16x8*>(&Vb[(f * 16 + lm) * 40 + g * 8]);
            const bf16x8 vl = *reinterpret_cast<const bf16x8*>(&Vb[3200 + (f * 16 + lm) * 40 + g * 8]);
            accO[f] = MFMA16(pa, vh, accO[f]);
            accO[f] = MFMA16(pa, vl, accO[f]);
        }

        // all my LDS reads delivered -> buf free; then refill it for ti+2
        asm volatile("s_waitcnt lgkmcnt(0)" ::: "memory");
        __builtin_amdgcn_s_barrier();
        asm volatile("" ::: "memory");
        if (ti + 2 < ntiles) issue(buf, t0 + ti + 2);
    }

    // ---- epilogue: redistribute 1/l to O-fragment rows, write packed A'
    const float linv = 1.f / lrow;
    float invq[4];
    #pragma unroll
    for (int r = 0; r < 4; ++r) invq[r] = __shfl(linv, ((lane >> 4) << 2) + r);

    #pragma unroll
    for (int r = 0; r < 4; ++r) {
        const int n = q0 + w * 16 + g * 4 + r;
        const size_t rb = (size_t)n * KP + h * HD;
        #pragma unroll
        for (int f = 0; f < 5; ++f) {
            const float v = accO[f][r] * invq[r];
            const unsigned short hi = f2bf(v);
            const unsigned short lo = f2bf(v - bf2f(hi));
            Ap[rb + f * 16 + lm]            = hi;
            Ap[rb + DIMM + f * 16 + lm]     = lo;
            Ap[rb + 2 * DIMM + f * 16 + lm] = hi;
        }
    }
    #undef SEGOF
}

// ---------------------------------------------------------------------------
extern "C" void kernel_launch(void* const* d_in, const int* in_sizes, int n_in,
                              void* d_out, int out_size, void* d_ws, size_t ws_size,
                              hipStream_t stream)
{
    const float* hidden = (const float*)d_in[0];
    const int*   cu     = (const int*)  d_in[1];
    const float* rope   = (const float*)d_in[2];
    const float* w_qkv  = (const float*)d_in[3];
    const float* b_qkv  = (const float*)d_in[4];
    const float* w_proj = (const float*)d_in[5];
    const float* b_proj = (const float*)d_in[6];
    float*       out    = (float*)d_out;

    const size_t perbuf = (size_t)NHEAD * N_TOK * HD;          // 5,242,880 floats
    float* qbuf = (float*)d_ws;
    float* kbuf = qbuf + perbuf;
    float* vbuf = kbuf + perbuf;
    unsigned short* Apack = (unsigned short*)(vbuf + perbuf);  // [4096][3840]
    unsigned short* BtQ   = Apack + (size_t)N_TOK * KP;        // [3840][3840]
    unsigned short* BtP   = BtQ + (size_t)QKVN * KP;           // [1280][3840]
    unsigned short* Vt    = BtP + (size_t)DIMM * KP;           // [16][128][2][80][40]
    unsigned short* Kpk   = BtQ;   // overlay: BtQ dead after qkv GEMM

    pack_A_kernel<<<(N_TOK * DIMM / 4 + 255) / 256, 256, 0, stream>>>(hidden, Apack);
    pack_Bt_kernel<<<dim3(DIMM / 32, QKVN / 32), 256, 0, stream>>>(w_qkv, BtQ, QKVN);
    pack_Bt_kernel<<<dim3(DIMM / 32, DIMM / 32), 256, 0, stream>>>(w_proj, BtP, DIMM);

    gemm_mfma<1><<<960, 256, 0, stream>>>(Apack, BtQ, b_qkv, qbuf, QKVN);

    rope_kernel<<<(N_TOK * NHEAD * 40 + 255) / 256, 256, 0, stream>>>(rope, qbuf, kbuf, Kpk);
    vpack_kernel<<<dim3(128, NHEAD), 256, 0, stream>>>(vbuf, Vt);

    attn_mfma<<<1024, 256, 0, stream>>>(qbuf, Kpk, Vt, cu, Apack);

    gemm_mfma<0><<<320, 256, 0, stream>>>(Apack, BtP, b_proj, out, DIMM);
}